// Round 6
// baseline (542.610 us; speedup 1.0000x reference)
//
#include <hip/hip_runtime.h>

#define SPAT 32768   // 32*32*32
#define BATCH 2
#define GN_EPS 1e-5f

// =====================================================================
// Register-GEMM 1x1x1 conv: thread = 1 position, ALL COUT in registers.
// Input read EXACTLY once. Weight idx: c uniform, o static -> s_load.
// grid: (SPAT/256, 1, B), block 256
// =====================================================================
template <int CIN, int COUT, bool RELU>
__global__ __launch_bounds__(256) void k_rc1(
    const float* __restrict__ in, const float* __restrict__ w,
    const float* __restrict__ sc, const float* __restrict__ bi,
    float* __restrict__ out)
{
    int pos = blockIdx.x * 256 + threadIdx.x;
    int b = blockIdx.z;
    const float* ip = in + (size_t)b * CIN * SPAT + pos;
    float acc[COUT];
#pragma unroll
    for (int o = 0; o < COUT; ++o) acc[o] = 0.f;
#pragma unroll 4
    for (int c = 0; c < CIN; ++c) {
        float v = ip[(size_t)c * SPAT];
#pragma unroll
        for (int o = 0; o < COUT; ++o)
            acc[o] = fmaf(v, w[o * CIN + c], acc[o]);
    }
    float* op = out + (size_t)b * COUT * SPAT + pos;
#pragma unroll
    for (int o = 0; o < COUT; ++o) {
        float r = acc[o] * sc[o] + bi[o];
        if (RELU) r = fmaxf(r, 0.f);
        op[(size_t)o * SPAT] = r;
    }
}

// =====================================================================
// cv4 (32->216) + bias, register-GEMM, 54-output chunks (blockIdx.y).
// grid: (SPAT/256, 4, B), block 256. a1 read 4x total (was 27x).
// =====================================================================
__global__ __launch_bounds__(256) void k_cv4r(
    const float* __restrict__ a, const float* __restrict__ w4,
    const float* __restrict__ b4, float* __restrict__ wk)
{
    int pos = blockIdx.x * 256 + threadIdx.x;
    int o0 = blockIdx.y * 54, b = blockIdx.z;
    const float* ip = a + (size_t)b * 32 * SPAT + pos;
    float acc[54];
#pragma unroll
    for (int j = 0; j < 54; ++j) acc[j] = 0.f;
#pragma unroll 4
    for (int c = 0; c < 32; ++c) {
        float v = ip[(size_t)c * SPAT];
#pragma unroll
        for (int j = 0; j < 54; ++j)
            acc[j] = fmaf(v, w4[(o0 + j) * 32 + c], acc[j]);
    }
    float* op = wk + ((size_t)b * 216 + o0) * SPAT + pos;
#pragma unroll
    for (int j = 0; j < 54; ++j)
        op[(size_t)j * SPAT] = acc[j] + b4[o0 + j];
}

// =====================================================================
// Fused FFN in registers: pw1 + BN + ReLU + pw2 + BN + residual.
// Thread = 1 position: y[64] regs, acc[64] regs, f chunks of 16.
// f1 NEVER exists. fc0 loop rolled so body (~2K fma) fits I$.
// grid: (SPAT/256, 1, B), block 256
// =====================================================================
__global__ __launch_bounds__(256) void k_ffn(
    const float* __restrict__ yin,
    const float* __restrict__ w1v, const float* __restrict__ s1v,
    const float* __restrict__ b1v,
    const float* __restrict__ w2v, const float* __restrict__ s2v,
    const float* __restrict__ b2v,
    float* __restrict__ out)
{
    int pos = blockIdx.x * 256 + threadIdx.x;
    int b = blockIdx.z;
    const float* ip = yin + (size_t)b * 64 * SPAT + pos;
    float y[64];
#pragma unroll
    for (int c = 0; c < 64; ++c) y[c] = ip[(size_t)c * SPAT];
    float acc[64];
#pragma unroll
    for (int o = 0; o < 64; ++o) acc[o] = 0.f;
#pragma unroll 1
    for (int fc0 = 0; fc0 < 128; fc0 += 16) {
        float f[16];
#pragma unroll
        for (int j = 0; j < 16; ++j) {
            float a = 0.f;
#pragma unroll
            for (int c = 0; c < 64; ++c)
                a = fmaf(y[c], w1v[(fc0 + j) * 64 + c], a);
            a = a * s1v[fc0 + j] + b1v[fc0 + j];
            f[j] = fmaxf(a, 0.f);
        }
#pragma unroll
        for (int o = 0; o < 64; ++o) {
            float a = acc[o];
#pragma unroll
            for (int j = 0; j < 16; ++j)
                a = fmaf(f[j], w2v[o * 128 + fc0 + j], a);
            acc[o] = a;
        }
    }
    float* op = out + (size_t)b * 64 * SPAT + pos;
#pragma unroll
    for (int o = 0; o < 64; ++o)
        op[(size_t)o * SPAT] = acc[o] * s2v[o] + b2v[o] + y[o];
}

// =====================================================================
// Gram partials of a1: G[m][m'] and S[m] per 256-pos chunk (determinism)
// grid: (128, 1, B), block 256
// =====================================================================
__global__ __launch_bounds__(256) void k_gram(
    const float* __restrict__ a, float* __restrict__ partial)
{
    __shared__ float lds[32 * 257];
    int blk = blockIdx.x, b = blockIdx.z;
    const float* ap = a + (size_t)b * 32 * SPAT + blk * 256;
    for (int i = threadIdx.x; i < 32 * 64; i += 256) {
        int m = i >> 6, p4 = (i & 63) * 4;
        float4 v = *(const float4*)(ap + (size_t)m * SPAT + p4);
        lds[m * 257 + p4 + 0] = v.x; lds[m * 257 + p4 + 1] = v.y;
        lds[m * 257 + p4 + 2] = v.z; lds[m * 257 + p4 + 3] = v.w;
    }
    __syncthreads();
    float* outp = partial + (size_t)(b * 128 + blk) * 1056;
#pragma unroll
    for (int it = 0; it < 4; ++it) {
        int pid = threadIdx.x + it * 256;
        const float* pa = &lds[(pid >> 5) * 257];
        const float* pb = &lds[(pid & 31) * 257];
        float acc = 0.f;
#pragma unroll 8
        for (int p = 0; p < 256; ++p) acc = fmaf(pa[p], pb[p], acc);
        outp[pid] = acc;
    }
    if (threadIdx.x < 32) {
        const float* pa = &lds[threadIdx.x * 257];
        float scc = 0.f;
#pragma unroll 8
        for (int p = 0; p < 256; ++p) scc += pa[p];
        outp[1024 + threadIdx.x] = scc;
    }
}

// =====================================================================
// GN stats from Gram: stats[bg] = {mu, inv}
// =====================================================================
__global__ __launch_bounds__(512) void k_stats(
    const float* __restrict__ partial, const float* __restrict__ w4,
    const float* __restrict__ b4, float* __restrict__ stats)
{
    __shared__ float G[2 * 1056];
    __shared__ float sred[432], ssred[432];
    for (int e = threadIdx.x; e < 2 * 1056; e += 512) {
        int b = e / 1056, pid = e % 1056;
        float acc = 0.f;
#pragma unroll 8
        for (int blk = 0; blk < 128; ++blk)
            acc += partial[(size_t)(b * 128 + blk) * 1056 + pid];
        G[e] = acc;
    }
    __syncthreads();
    if (threadIdx.x < 432) {
        int t = threadIdx.x;
        int b = t / 216, r = t % 216, g = r / 27, k = r % 27;
        const float* wk = w4 + (g * 27 + k) * 32;
        float wreg[32];
#pragma unroll
        for (int m = 0; m < 32; ++m) wreg[m] = wk[m];
        const float* Gb = &G[b * 1056];
        const float* Sb = &G[b * 1056 + 1024];
        float sk = 0.f, ssk = 0.f;
#pragma unroll
        for (int m = 0; m < 32; ++m) {
            sk = fmaf(wreg[m], Sb[m], sk);
            float dot = 0.f;
#pragma unroll
            for (int mm = 0; mm < 32; ++mm)
                dot = fmaf(wreg[mm], Gb[m * 32 + mm], dot);
            ssk = fmaf(wreg[m], dot, ssk);
        }
        float bb = b4[g * 27 + k];
        float NN = (float)SPAT;
        ssk += 2.f * bb * sk + NN * bb * bb;
        sk  += NN * bb;
        sred[t] = sk; ssred[t] = ssk;
    }
    __syncthreads();
    if (threadIdx.x < 16) {
        int bg = threadIdx.x;
        float s = 0.f, ss = 0.f;
        for (int k = 0; k < 27; ++k) { s += sred[bg * 27 + k]; ss += ssred[bg * 27 + k]; }
        float N27 = 27.f * (float)SPAT;
        float mu = s / N27;
        float var = ss / N27 - mu * mu;
        stats[bg * 2 + 0] = mu;
        stats[bg * 2 + 1] = rsqrtf(var + GN_EPS);
    }
}

// =====================================================================
// SKA: group-major, float4 quads, shuffle wrap, in-register GN normalize.
// grid: (SPAT/1024, 8 groups, B), block 256. (round-0-proven structure)
// =====================================================================
__global__ __launch_bounds__(256) void k_ska(
    const float* __restrict__ x, const float* __restrict__ wk,
    const float* __restrict__ stats,
    const float* __restrict__ gn_g, const float* __restrict__ gn_b,
    const float* __restrict__ bn_s, const float* __restrict__ bn_b,
    float* __restrict__ y)
{
    int q = blockIdx.x * 256 + threadIdx.x;
    int s = q * 4;
    int g = blockIdx.y, b = blockIdx.z;
    int bg = b * 8 + g;
    float mu  = stats[bg * 2 + 0];
    float inv = stats[bg * 2 + 1];
    int d = s >> 10, h = (s >> 5) & 31, w0 = s & 31;
    int lane = threadIdx.x & 63;
    int xl_src = (lane & 56) | ((lane + 7) & 7);
    int xr_src = (lane & 56) | ((lane + 1) & 7);
    const float* xg = x + ((size_t)(b * 64 + g * 8)) * SPAT;
    const float* wp = wk + ((size_t)(b * 216 + g * 27)) * SPAT + s;

    float4 acc[8];
    float4 xc[8];
#pragma unroll
    for (int c = 0; c < 8; ++c) acc[c] = {0.f, 0.f, 0.f, 0.f};

#pragma unroll
    for (int kd = 0; kd < 3; ++kd) {
        int zd = (d + kd + 31) & 31;
#pragma unroll
        for (int kh = 0; kh < 3; ++kh) {
            int zh = (h + kh + 31) & 31;
            int kbase = (kd * 3 + kh) * 3;
            float wn[3][4];
#pragma unroll
            for (int kw = 0; kw < 3; ++kw) {
                int kk = kbase + kw;
                float4 wq = *(const float4*)(wp + (size_t)kk * SPAT);
                float A = gn_g[g * 27 + kk] * inv;
                float B = gn_b[g * 27 + kk] - mu * A;
                wn[kw][0] = wq.x * A + B;
                wn[kw][1] = wq.y * A + B;
                wn[kw][2] = wq.z * A + B;
                wn[kw][3] = wq.w * A + B;
            }
            int rowoff = zd * 1024 + zh * 32;
            bool center = (kd == 1) && (kh == 1);
#pragma unroll
            for (int c = 0; c < 8; ++c) {
                float4 m = *(const float4*)(xg + (size_t)c * SPAT + rowoff + w0);
                if (center) xc[c] = m;
                float xl = __shfl(m.w, xl_src, 64);
                float xr = __shfl(m.x, xr_src, 64);
                float win[6] = {xl, m.x, m.y, m.z, m.w, xr};
#pragma unroll
                for (int kw = 0; kw < 3; ++kw) {
                    acc[c].x = fmaf(win[0 + kw], wn[kw][0], acc[c].x);
                    acc[c].y = fmaf(win[1 + kw], wn[kw][1], acc[c].y);
                    acc[c].z = fmaf(win[2 + kw], wn[kw][2], acc[c].z);
                    acc[c].w = fmaf(win[3 + kw], wn[kw][3], acc[c].w);
                }
            }
        }
    }
#pragma unroll
    for (int c = 0; c < 8; ++c) {
        int ch = g * 8 + c;
        float bs = bn_s[ch], bb = bn_b[ch];
        float4 r;
        r.x = acc[c].x * bs + bb + xc[c].x;
        r.y = acc[c].y * bs + bb + xc[c].y;
        r.z = acc[c].z * bs + bb + xc[c].z;
        r.w = acc[c].w * bs + bb + xc[c].w;
        *(float4*)(y + ((size_t)(b * 64 + ch)) * SPAT + s) = r;
    }
}

// =====================================================================
// depthwise 5x5x5, zero pad 2, + affine, LDS-tiled (4 output planes)
// grid: (8, 32, B), block 256  (round-0-proven)
// =====================================================================
__global__ __launch_bounds__(256) void k_dw5(
    const float* __restrict__ in, const float* __restrict__ w2,
    const float* __restrict__ s2, const float* __restrict__ b2,
    float* __restrict__ out)
{
    __shared__ float lds[8 * 36 * 40];           // 46,080 B
    int tid = threadIdx.x;
    int d0 = blockIdx.x * 4;
    int c = blockIdx.y, b = blockIdx.z;
    const float* ip = in + ((size_t)(b * 32 + c)) * SPAT;

    float4 z = {0.f, 0.f, 0.f, 0.f};
    for (int i = tid; i < 8 * 36 * 40 / 4; i += 256)
        ((float4*)lds)[i] = z;
    __syncthreads();
    for (int i = tid; i < 8 * 256; i += 256) {
        int p = i >> 8, rem = i & 255;
        int r = rem >> 3, c4 = (rem & 7) * 4;
        int d = d0 - 2 + p;
        if (d >= 0 && d < 32) {
            float4 v = *(const float4*)(ip + d * 1024 + r * 32 + c4);
            *(float4*)&lds[p * 1440 + (r + 2) * 40 + (c4 + 4)] = v;
        }
    }
    __syncthreads();

    float scl = s2[c], shf = b2[c];
    const float* wt = w2 + c * 125;
#pragma unroll
    for (int k = 0; k < 4; ++k) {
        int j = tid + k * 256;
        int pd = j >> 8, rem = j & 255;
        int hr = rem >> 3, w4i = (rem & 7) * 4;
        float4 acc = {0.f, 0.f, 0.f, 0.f};
#pragma unroll
        for (int kd = 0; kd < 5; ++kd) {
            const float* pl = &lds[(pd + kd) * 1440];
#pragma unroll
            for (int kh = 0; kh < 5; ++kh) {
                const float* row = pl + (hr + kh) * 40 + w4i;
                float4 r0 = *(const float4*)(row);
                float4 r1 = *(const float4*)(row + 4);
                float4 r2 = *(const float4*)(row + 8);
                float win[12] = {r0.x, r0.y, r0.z, r0.w,
                                 r1.x, r1.y, r1.z, r1.w,
                                 r2.x, r2.y, r2.z, r2.w};
#pragma unroll
                for (int kw = 0; kw < 5; ++kw) {
                    float wv = wt[kd * 25 + kh * 5 + kw];
                    acc.x = fmaf(wv, win[2 + 0 + kw], acc.x);
                    acc.y = fmaf(wv, win[2 + 1 + kw], acc.y);
                    acc.z = fmaf(wv, win[2 + 2 + kw], acc.z);
                    acc.w = fmaf(wv, win[2 + 3 + kw], acc.w);
                }
            }
        }
        acc.x = acc.x * scl + shf; acc.y = acc.y * scl + shf;
        acc.z = acc.z * scl + shf; acc.w = acc.w * scl + shf;
        *(float4*)(out + ((size_t)(b * 32 + c)) * SPAT
                   + (d0 + pd) * 1024 + hr * 32 + w4i) = acc;
    }
}

extern "C" void kernel_launch(void* const* d_in, const int* in_sizes, int n_in,
                              void* d_out, int out_size, void* d_ws, size_t ws_size,
                              hipStream_t stream)
{
    const float* x     = (const float*)d_in[0];
    const float* w1    = (const float*)d_in[1];
    const float* s1    = (const float*)d_in[2];
    const float* b1    = (const float*)d_in[3];
    const float* w2    = (const float*)d_in[4];
    const float* s2    = (const float*)d_in[5];
    const float* b2    = (const float*)d_in[6];
    const float* w3    = (const float*)d_in[7];
    const float* s3    = (const float*)d_in[8];
    const float* b3    = (const float*)d_in[9];
    const float* w4    = (const float*)d_in[10];
    const float* b4    = (const float*)d_in[11];
    const float* gn_g  = (const float*)d_in[12];
    const float* gn_b  = (const float*)d_in[13];
    const float* bn_s  = (const float*)d_in[14];
    const float* bn_b  = (const float*)d_in[15];
    const float* pw1_w = (const float*)d_in[16];
    const float* pw1_s = (const float*)d_in[17];
    const float* pw1_b = (const float*)d_in[18];
    const float* pw2_w = (const float*)d_in[19];
    const float* pw2_s = (const float*)d_in[20];
    const float* pw2_b = (const float*)d_in[21];

    // Workspace ~74.5 MB, lifetime-overlapped (f1 no longer exists):
    //   [0,16MB):  a1 | a2 (LKP), later y (SKA/FFN)
    //   [16MB..):  wk (56.6MB), then gram partials + stats at the tail
    float* ws    = (float*)d_ws;
    float* a1    = ws;                                   // 8 MB
    float* a2    = a1 + (size_t)BATCH * 32 * SPAT;       // 8 MB
    float* yb    = ws;                                   // 16 MB (over a1,a2)
    float* wkb   = ws + (size_t)BATCH * 64 * SPAT;       // 56.6 MB
    float* part  = wkb + (size_t)BATCH * 216 * SPAT;     // 1.08 MB
    float* stats = part + (size_t)256 * 1056;            // 32 floats

    dim3 blk(256);
    // cv1 + BN + ReLU : 64 -> 32  (register-GEMM, x read once)
    k_rc1<64, 32, true><<<dim3(SPAT / 256, 1, BATCH), blk, 0, stream>>>(
        x, w1, s1, b1, a1);
    // dw 5^3 + BN (LDS-tiled, 4 planes/block)
    k_dw5<<<dim3(8, 32, BATCH), blk, 0, stream>>>(a1, w2, s2, b2, a2);
    // cv3 + BN + ReLU : 32 -> 32  (register-GEMM)
    k_rc1<32, 32, true><<<dim3(SPAT / 256, 1, BATCH), blk, 0, stream>>>(
        a2, w3, s3, b3, a1);
    // GN stats via Gram linearity (reads a1 once)
    k_gram<<<dim3(128, 1, BATCH), blk, 0, stream>>>(a1, part);
    k_stats<<<dim3(1), dim3(512), 0, stream>>>(part, w4, b4, stats);
    // cv4 + bias : 32 -> 216 raw wk (register-GEMM, 54-out chunks)
    k_cv4r<<<dim3(SPAT / 256, 4, BATCH), blk, 0, stream>>>(
        a1, w4, b4, wkb);
    // SKA + in-register GN + BN + residual -> y
    k_ska<<<dim3(SPAT / 1024, 8, BATCH), blk, 0, stream>>>(
        x, wkb, stats, gn_g, gn_b, bn_s, bn_b, yb);
    // FFN fused in registers: pw1+BN+ReLU+pw2+BN+residual -> out
    k_ffn<<<dim3(SPAT / 256, 1, BATCH), blk, 0, stream>>>(
        yb, pw1_w, pw1_s, pw1_b, pw2_w, pw2_s, pw2_b, (float*)d_out);
}

// Round 7
// 270.154 us; speedup vs baseline: 2.0085x; 2.0085x over previous
//
#include <hip/hip_runtime.h>

#define SPAT 32768   // 32*32*32
#define BATCH 2
#define GN_EPS 1e-5f

__device__ __forceinline__ void fma4(float4& a, const float4& v, float w) {
    a.x = fmaf(v.x, w, a.x); a.y = fmaf(v.y, w, a.y);
    a.z = fmaf(v.z, w, a.z); a.w = fmaf(v.w, w, a.w);
}

// =====================================================================
// 1x1x1 conv: float4 spatial x NO output channels. o0 is BLOCK-uniform
// (blockIdx.y) so weight reads compile to s_load.
// grid: (SPAT/1024, Cout/NO, B), block 256
// =====================================================================
template <int CIN, int NO, bool RELU, bool AFF>
__global__ __launch_bounds__(256) void k_c1(
    const float* __restrict__ in, const float* __restrict__ w,
    const float* __restrict__ sc, const float* __restrict__ bi,
    float* __restrict__ out, int Cout)
{
    int q = blockIdx.x * 256 + threadIdx.x;
    int s = q * 4;
    int o0 = blockIdx.y * NO, b = blockIdx.z;
    const float* ip = in + (size_t)b * CIN * SPAT + s;
    float4 acc[NO];
#pragma unroll
    for (int i = 0; i < NO; ++i) acc[i] = {0.f, 0.f, 0.f, 0.f};
#pragma unroll 4
    for (int c = 0; c < CIN; ++c) {
        float4 v = *(const float4*)(ip + (size_t)c * SPAT);
#pragma unroll
        for (int i = 0; i < NO; ++i)
            fma4(acc[i], v, w[(o0 + i) * CIN + c]);
    }
#pragma unroll
    for (int i = 0; i < NO; ++i) {
        int o = o0 + i;
        float scale = AFF ? sc[o] : 1.f;
        float shift = bi[o];
        float4 r = acc[i];
        r.x = r.x * scale + shift; r.y = r.y * scale + shift;
        r.z = r.z * scale + shift; r.w = r.w * scale + shift;
        if (RELU) {
            r.x = fmaxf(r.x, 0.f); r.y = fmaxf(r.y, 0.f);
            r.z = fmaxf(r.z, 0.f); r.w = fmaxf(r.w, 0.f);
        }
        *(float4*)(out + ((size_t)b * Cout + o) * SPAT + s) = r;
    }
}

// =====================================================================
// Gram partials of a1: G[m][m'] and S[m] per 256-pos chunk (determinism)
// grid: (128, 1, B), block 256
// =====================================================================
__global__ __launch_bounds__(256) void k_gram(
    const float* __restrict__ a, float* __restrict__ partial)
{
    __shared__ float lds[32 * 257];
    int blk = blockIdx.x, b = blockIdx.z;
    const float* ap = a + (size_t)b * 32 * SPAT + blk * 256;
    for (int i = threadIdx.x; i < 32 * 64; i += 256) {
        int m = i >> 6, p4 = (i & 63) * 4;
        float4 v = *(const float4*)(ap + (size_t)m * SPAT + p4);
        lds[m * 257 + p4 + 0] = v.x; lds[m * 257 + p4 + 1] = v.y;
        lds[m * 257 + p4 + 2] = v.z; lds[m * 257 + p4 + 3] = v.w;
    }
    __syncthreads();
    float* outp = partial + (size_t)(b * 128 + blk) * 1056;
#pragma unroll
    for (int it = 0; it < 4; ++it) {
        int pid = threadIdx.x + it * 256;
        const float* pa = &lds[(pid >> 5) * 257];
        const float* pb = &lds[(pid & 31) * 257];
        float acc = 0.f;
#pragma unroll 8
        for (int p = 0; p < 256; ++p) acc = fmaf(pa[p], pb[p], acc);
        outp[pid] = acc;
    }
    if (threadIdx.x < 32) {
        const float* pa = &lds[threadIdx.x * 257];
        float scc = 0.f;
#pragma unroll 8
        for (int p = 0; p < 256; ++p) scc += pa[p];
        outp[1024 + threadIdx.x] = scc;
    }
}

// =====================================================================
// GN stats from Gram: stats[bg] = {mu, inv}
// =====================================================================
__global__ __launch_bounds__(512) void k_stats(
    const float* __restrict__ partial, const float* __restrict__ w4,
    const float* __restrict__ b4, float* __restrict__ stats)
{
    __shared__ float G[2 * 1056];
    __shared__ float sred[432], ssred[432];
    for (int e = threadIdx.x; e < 2 * 1056; e += 512) {
        int b = e / 1056, pid = e % 1056;
        float acc = 0.f;
#pragma unroll 8
        for (int blk = 0; blk < 128; ++blk)
            acc += partial[(size_t)(b * 128 + blk) * 1056 + pid];
        G[e] = acc;
    }
    __syncthreads();
    if (threadIdx.x < 432) {
        int t = threadIdx.x;
        int b = t / 216, r = t % 216, g = r / 27, k = r % 27;
        const float* wk = w4 + (g * 27 + k) * 32;
        float wreg[32];
#pragma unroll
        for (int m = 0; m < 32; ++m) wreg[m] = wk[m];
        const float* Gb = &G[b * 1056];
        const float* Sb = &G[b * 1056 + 1024];
        float sk = 0.f, ssk = 0.f;
#pragma unroll
        for (int m = 0; m < 32; ++m) {
            sk = fmaf(wreg[m], Sb[m], sk);
            float dot = 0.f;
#pragma unroll
            for (int mm = 0; mm < 32; ++mm)
                dot = fmaf(wreg[mm], Gb[m * 32 + mm], dot);
            ssk = fmaf(wreg[m], dot, ssk);
        }
        float bb = b4[g * 27 + k];
        float NN = (float)SPAT;
        ssk += 2.f * bb * sk + NN * bb * bb;
        sk  += NN * bb;
        sred[t] = sk; ssred[t] = ssk;
    }
    __syncthreads();
    if (threadIdx.x < 16) {
        int bg = threadIdx.x;
        float s = 0.f, ss = 0.f;
        for (int k = 0; k < 27; ++k) { s += sred[bg * 27 + k]; ss += ssred[bg * 27 + k]; }
        float N27 = 27.f * (float)SPAT;
        float mu = s / N27;
        float var = ss / N27 - mu * mu;
        stats[bg * 2 + 0] = mu;
        stats[bg * 2 + 1] = rsqrtf(var + GN_EPS);
    }
}

// =====================================================================
// SKA: group-major, float4 quads, shuffle wrap, in-register GN normalize.
// grid: (SPAT/1024, 8 groups, B), block 256. (round-0-proven structure)
// =====================================================================
__global__ __launch_bounds__(256) void k_ska(
    const float* __restrict__ x, const float* __restrict__ wk,
    const float* __restrict__ stats,
    const float* __restrict__ gn_g, const float* __restrict__ gn_b,
    const float* __restrict__ bn_s, const float* __restrict__ bn_b,
    float* __restrict__ y)
{
    int q = blockIdx.x * 256 + threadIdx.x;
    int s = q * 4;
    int g = blockIdx.y, b = blockIdx.z;
    int bg = b * 8 + g;
    float mu  = stats[bg * 2 + 0];
    float inv = stats[bg * 2 + 1];
    int d = s >> 10, h = (s >> 5) & 31, w0 = s & 31;
    int lane = threadIdx.x & 63;
    int xl_src = (lane & 56) | ((lane + 7) & 7);
    int xr_src = (lane & 56) | ((lane + 1) & 7);
    const float* xg = x + ((size_t)(b * 64 + g * 8)) * SPAT;
    const float* wp = wk + ((size_t)(b * 216 + g * 27)) * SPAT + s;

    float4 acc[8];
    float4 xc[8];
#pragma unroll
    for (int c = 0; c < 8; ++c) acc[c] = {0.f, 0.f, 0.f, 0.f};

#pragma unroll
    for (int kd = 0; kd < 3; ++kd) {
        int zd = (d + kd + 31) & 31;
#pragma unroll
        for (int kh = 0; kh < 3; ++kh) {
            int zh = (h + kh + 31) & 31;
            int kbase = (kd * 3 + kh) * 3;
            float wn[3][4];
#pragma unroll
            for (int kw = 0; kw < 3; ++kw) {
                int kk = kbase + kw;
                float4 wq = *(const float4*)(wp + (size_t)kk * SPAT);
                float A = gn_g[g * 27 + kk] * inv;
                float B = gn_b[g * 27 + kk] - mu * A;
                wn[kw][0] = wq.x * A + B;
                wn[kw][1] = wq.y * A + B;
                wn[kw][2] = wq.z * A + B;
                wn[kw][3] = wq.w * A + B;
            }
            int rowoff = zd * 1024 + zh * 32;
            bool center = (kd == 1) && (kh == 1);
#pragma unroll
            for (int c = 0; c < 8; ++c) {
                float4 m = *(const float4*)(xg + (size_t)c * SPAT + rowoff + w0);
                if (center) xc[c] = m;
                float xl = __shfl(m.w, xl_src, 64);
                float xr = __shfl(m.x, xr_src, 64);
                float win[6] = {xl, m.x, m.y, m.z, m.w, xr};
#pragma unroll
                for (int kw = 0; kw < 3; ++kw) {
                    acc[c].x = fmaf(win[0 + kw], wn[kw][0], acc[c].x);
                    acc[c].y = fmaf(win[1 + kw], wn[kw][1], acc[c].y);
                    acc[c].z = fmaf(win[2 + kw], wn[kw][2], acc[c].z);
                    acc[c].w = fmaf(win[3 + kw], wn[kw][3], acc[c].w);
                }
            }
        }
    }
#pragma unroll
    for (int c = 0; c < 8; ++c) {
        int ch = g * 8 + c;
        float bs = bn_s[ch], bb = bn_b[ch];
        float4 r;
        r.x = acc[c].x * bs + bb + xc[c].x;
        r.y = acc[c].y * bs + bb + xc[c].y;
        r.z = acc[c].z * bs + bb + xc[c].z;
        r.w = acc[c].w * bs + bb + xc[c].w;
        *(float4*)(y + ((size_t)(b * 64 + ch)) * SPAT + s) = r;
    }
}

// =====================================================================
// depthwise 5x5x5, zero pad 2, + affine, LDS-tiled (4 output planes)
// grid: (8, 32, B), block 256  (round-0-proven)
// =====================================================================
__global__ __launch_bounds__(256) void k_dw5(
    const float* __restrict__ in, const float* __restrict__ w2,
    const float* __restrict__ s2, const float* __restrict__ b2,
    float* __restrict__ out)
{
    __shared__ float lds[8 * 36 * 40];           // 46,080 B
    int tid = threadIdx.x;
    int d0 = blockIdx.x * 4;
    int c = blockIdx.y, b = blockIdx.z;
    const float* ip = in + ((size_t)(b * 32 + c)) * SPAT;

    float4 z = {0.f, 0.f, 0.f, 0.f};
    for (int i = tid; i < 8 * 36 * 40 / 4; i += 256)
        ((float4*)lds)[i] = z;
    __syncthreads();
    for (int i = tid; i < 8 * 256; i += 256) {
        int p = i >> 8, rem = i & 255;
        int r = rem >> 3, c4 = (rem & 7) * 4;
        int d = d0 - 2 + p;
        if (d >= 0 && d < 32) {
            float4 v = *(const float4*)(ip + d * 1024 + r * 32 + c4);
            *(float4*)&lds[p * 1440 + (r + 2) * 40 + (c4 + 4)] = v;
        }
    }
    __syncthreads();

    float scl = s2[c], shf = b2[c];
    const float* wt = w2 + c * 125;
#pragma unroll
    for (int k = 0; k < 4; ++k) {
        int j = tid + k * 256;
        int pd = j >> 8, rem = j & 255;
        int hr = rem >> 3, w4i = (rem & 7) * 4;
        float4 acc = {0.f, 0.f, 0.f, 0.f};
#pragma unroll
        for (int kd = 0; kd < 5; ++kd) {
            const float* pl = &lds[(pd + kd) * 1440];
#pragma unroll
            for (int kh = 0; kh < 5; ++kh) {
                const float* row = pl + (hr + kh) * 40 + w4i;
                float4 r0 = *(const float4*)(row);
                float4 r1 = *(const float4*)(row + 4);
                float4 r2 = *(const float4*)(row + 8);
                float win[12] = {r0.x, r0.y, r0.z, r0.w,
                                 r1.x, r1.y, r1.z, r1.w,
                                 r2.x, r2.y, r2.z, r2.w};
#pragma unroll
                for (int kw = 0; kw < 5; ++kw) {
                    float wv = wt[kd * 25 + kh * 5 + kw];
                    acc.x = fmaf(wv, win[2 + 0 + kw], acc.x);
                    acc.y = fmaf(wv, win[2 + 1 + kw], acc.y);
                    acc.z = fmaf(wv, win[2 + 2 + kw], acc.z);
                    acc.w = fmaf(wv, win[2 + 3 + kw], acc.w);
                }
            }
        }
        acc.x = acc.x * scl + shf; acc.y = acc.y * scl + shf;
        acc.z = acc.z * scl + shf; acc.w = acc.w * scl + shf;
        *(float4*)(out + ((size_t)(b * 32 + c)) * SPAT
                   + (d0 + pd) * 1024 + hr * 32 + w4i) = acc;
    }
}

// =====================================================================
// pw2 (128->64) + affine + residual, float4, NO outs, block-uniform o0
// grid: (SPAT/1024, 64/NO, B), block 256
// =====================================================================
template <int NO>
__global__ __launch_bounds__(256) void k_pw2_out(
    const float* __restrict__ f1, const float* __restrict__ w,
    const float* __restrict__ sc, const float* __restrict__ bi,
    const float* __restrict__ yres, float* __restrict__ out)
{
    int q = blockIdx.x * 256 + threadIdx.x;
    int s = q * 4;
    int o0 = blockIdx.y * NO, b = blockIdx.z;
    const float* ip = f1 + (size_t)b * 128 * SPAT + s;
    float4 acc[NO];
#pragma unroll
    for (int i = 0; i < NO; ++i) acc[i] = {0.f, 0.f, 0.f, 0.f};
#pragma unroll 4
    for (int c = 0; c < 128; ++c) {
        float4 v = *(const float4*)(ip + (size_t)c * SPAT);
#pragma unroll
        for (int i = 0; i < NO; ++i)
            fma4(acc[i], v, w[(o0 + i) * 128 + c]);
    }
#pragma unroll
    for (int i = 0; i < NO; ++i) {
        int o = o0 + i;
        float scale = sc[o], shift = bi[o];
        float4 yv = *(const float4*)(yres + ((size_t)(b * 64 + o)) * SPAT + s);
        float4 r = acc[i];
        r.x = r.x * scale + shift + yv.x;
        r.y = r.y * scale + shift + yv.y;
        r.z = r.z * scale + shift + yv.z;
        r.w = r.w * scale + shift + yv.w;
        *(float4*)(out + ((size_t)(b * 64 + o)) * SPAT + s) = r;
    }
}

extern "C" void kernel_launch(void* const* d_in, const int* in_sizes, int n_in,
                              void* d_out, int out_size, void* d_ws, size_t ws_size,
                              hipStream_t stream)
{
    const float* x     = (const float*)d_in[0];
    const float* w1    = (const float*)d_in[1];
    const float* s1    = (const float*)d_in[2];
    const float* b1    = (const float*)d_in[3];
    const float* w2    = (const float*)d_in[4];
    const float* s2    = (const float*)d_in[5];
    const float* b2    = (const float*)d_in[6];
    const float* w3    = (const float*)d_in[7];
    const float* s3    = (const float*)d_in[8];
    const float* b3    = (const float*)d_in[9];
    const float* w4    = (const float*)d_in[10];
    const float* b4    = (const float*)d_in[11];
    const float* gn_g  = (const float*)d_in[12];
    const float* gn_b  = (const float*)d_in[13];
    const float* bn_s  = (const float*)d_in[14];
    const float* bn_b  = (const float*)d_in[15];
    const float* pw1_w = (const float*)d_in[16];
    const float* pw1_s = (const float*)d_in[17];
    const float* pw1_b = (const float*)d_in[18];
    const float* pw2_w = (const float*)d_in[19];
    const float* pw2_s = (const float*)d_in[20];
    const float* pw2_b = (const float*)d_in[21];

    // Workspace ~73.7 MB, lifetime-overlapped (same layout as round-5, fits):
    //   [0,16MB):  a1 | a2 (LKP), later y (SKA/FFN)
    //   [16MB..):  wk (56.6MB) during cv4..ska, then f1 (32MB) for FFN
    //   tail: gram partials (1.08MB) + stats (32 floats)
    float* ws    = (float*)d_ws;
    float* a1    = ws;                                   // 8 MB
    float* a2    = a1 + (size_t)BATCH * 32 * SPAT;       // 8 MB
    float* yb    = ws;                                   // 16 MB (over a1,a2)
    float* wkb   = ws + (size_t)BATCH * 64 * SPAT;       // 56.6 MB
    float* f1    = wkb;                                  // 32 MB (over wk, after ska)
    float* part  = wkb + (size_t)BATCH * 216 * SPAT;     // 1.08 MB
    float* stats = part + (size_t)256 * 1056;            // 32 floats

    dim3 blk(256);
    // cv1 + BN + ReLU : 64 -> 32  (float4, 4 out/thread, 512 blocks)
    k_c1<64, 4, true, true><<<dim3(SPAT / 1024, 8, BATCH), blk, 0, stream>>>(
        x, w1, s1, b1, a1, 32);
    // dw 5^3 + BN (LDS-tiled, 4 planes/block)
    k_dw5<<<dim3(8, 32, BATCH), blk, 0, stream>>>(a1, w2, s2, b2, a2);
    // cv3 + BN + ReLU : 32 -> 32  (float4, 4 out/thread, 512 blocks)
    k_c1<32, 4, true, true><<<dim3(SPAT / 1024, 8, BATCH), blk, 0, stream>>>(
        a2, w3, s3, b3, a1, 32);
    // GN stats via Gram linearity (reads a1 once)
    k_gram<<<dim3(128, 1, BATCH), blk, 0, stream>>>(a1, part);
    k_stats<<<dim3(1), dim3(512), 0, stream>>>(part, w4, b4, stats);
    // cv4 + bias : 32 -> 216 raw wk  (float4, 8 out/thread, 1728 blocks)
    k_c1<32, 8, false, false><<<dim3(SPAT / 1024, 27, BATCH), blk, 0, stream>>>(
        a1, w4, nullptr, b4, wkb, 216);
    // SKA + in-register GN + BN + residual -> y
    k_ska<<<dim3(SPAT / 1024, 8, BATCH), blk, 0, stream>>>(
        x, wkb, stats, gn_g, gn_b, bn_s, bn_b, yb);
    // pw1 + BN + ReLU : 64 -> 128  (float4, 8 out/thread, 1024 blocks)
    k_c1<64, 8, true, true><<<dim3(SPAT / 1024, 16, BATCH), blk, 0, stream>>>(
        yb, pw1_w, pw1_s, pw1_b, f1, 128);
    // pw2 + BN + residual -> out  (float4, 8 out/thread, 512 blocks)
    k_pw2_out<8><<<dim3(SPAT / 1024, 8, BATCH), blk, 0, stream>>>(
        f1, pw2_w, pw2_s, pw2_b, yb, (float*)d_out);
}